// Round 1
// baseline (208.036 us; speedup 1.0000x reference)
//
#include <hip/hip_runtime.h>

#define PI2 6.28318530717958647692f

// ---------------------------------------------------------------------------
// Kernel 1: per (b,t) plane: X[128][128] -> Xf[32 kx][16 ky] (complex, /16384)
// kx modes: kxi 0..15 -> kx=kxi ; kxi 16..31 -> kx = kxi+96 (=112..127)
// Xf layout: [plane][kxi][ky][ri]  (1024 dwords per plane)
// ---------------------------------------------------------------------------
__global__ __launch_bounds__(256) void k_fwd(const float* __restrict__ X,
                                             float* __restrict__ Xf) {
  __shared__ float Xb[64][132];   // 64 staged rows, padded
  __shared__ float Ab[128][36];   // A[h][ky*2+ri], padded to 36
  const int plane = blockIdx.x;                 // b*64 + t
  const float* Xp = X + (size_t)plane * (128 * 128);
  const int tid = threadIdx.x;

  // row-DFT mapping: thread = (row, ky-group); ky set {kyg, kyg+4, kyg+8, kyg+12}
  const int hloc = tid >> 2;      // 0..63
  const int kyg  = tid & 3;
  const float sgn = (kyg & 1) ? -1.f : 1.f;   // parity of whole ky set
  float sr[4][4], si[4][4];       // s_ky^j, j=1..4, s = e^{-2pi i ky/128}
  #pragma unroll
  for (int e = 0; e < 4; ++e) {
    int ky = kyg + 4 * e;
    #pragma unroll
    for (int j = 1; j <= 4; ++j)
      __sincosf(-PI2 * (float)(ky * j) / 128.f, &si[e][j - 1], &sr[e][j - 1]);
  }

  for (int st = 0; st < 2; ++st) {
    const int hbase = st * 64;
    __syncthreads();
    // stage 64 rows, coalesced float4
    #pragma unroll
    for (int k = 0; k < 8; ++k) {
      int i = tid + k * 256;      // 0..2047 float4 slots
      int h = i >> 5, w4 = i & 31;
      float4 v = *(const float4*)(Xp + (size_t)(hbase + h) * 128 + w4 * 4);
      *(float4*)&Xb[h][w4 * 4] = v;
    }
    __syncthreads();
    // row DFT with radix-2 fold (w vs w+64) + unroll-4 twiddle powers
    float ar[4], ai[4], Tr[4], Ti[4];
    #pragma unroll
    for (int e = 0; e < 4; ++e) { ar[e] = ai[e] = 0.f; Tr[e] = 1.f; Ti[e] = 0.f; }
    #pragma unroll 4
    for (int g = 0; g < 16; ++g) {
      float4 xa  = *(float4*)&Xb[hloc][g * 4];
      float4 xb4 = *(float4*)&Xb[hloc][g * 4 + 64];
      float u0 = fmaf(sgn, xb4.x, xa.x);
      float u1 = fmaf(sgn, xb4.y, xa.y);
      float u2 = fmaf(sgn, xb4.z, xa.z);
      float u3 = fmaf(sgn, xb4.w, xa.w);
      #pragma unroll
      for (int e = 0; e < 4; ++e) {
        // v = u0 + u1 s + u2 s^2 + u3 s^3   (u real)
        float vr = u0 + u1 * sr[e][0] + u2 * sr[e][1] + u3 * sr[e][2];
        float vi =      u1 * si[e][0] + u2 * si[e][1] + u3 * si[e][2];
        ar[e] += Tr[e] * vr - Ti[e] * vi;
        ai[e] += Tr[e] * vi + Ti[e] * vr;
        float nr = Tr[e] * sr[e][3] - Ti[e] * si[e][3];   // T *= s^4
        float ni = Tr[e] * si[e][3] + Ti[e] * sr[e][3];
        Tr[e] = nr; Ti[e] = ni;
      }
    }
    const int h = hbase + hloc;
    #pragma unroll
    for (int e = 0; e < 4; ++e) {
      int ky = kyg + 4 * e;
      *(float2*)&Ab[h][2 * ky] = make_float2(ar[e], ai[e]);
    }
  }
  __syncthreads();

  // DFT over h: thread = (kx-pair, ky-pair); 128 active threads
  if (tid < 128) {
    const int kxp = tid >> 3;     // 0..15
    const int kyp = tid & 7;      // ky pair {2kyp, 2kyp+1}
    float cr_[2][2] = {}, ci_[2][2] = {};
    float wr2[2], wi2[2], Tr2[2], Ti2[2];
    const int kxa0 = kxp, kxa1 = kxp + 112;
    __sincosf(-PI2 * (float)kxa0 / 128.f, &wi2[0], &wr2[0]);
    __sincosf(-PI2 * (float)kxa1 / 128.f, &wi2[1], &wr2[1]);
    Tr2[0] = Tr2[1] = 1.f; Ti2[0] = Ti2[1] = 0.f;
    #pragma unroll 8
    for (int h = 0; h < 128; ++h) {
      float4 a = *(float4*)&Ab[h][4 * kyp];   // (Ar0,Ai0,Ar1,Ai1)
      #pragma unroll
      for (int e = 0; e < 2; ++e) {
        cr_[e][0] += a.x * Tr2[e] - a.y * Ti2[e];
        ci_[e][0] += a.x * Ti2[e] + a.y * Tr2[e];
        cr_[e][1] += a.z * Tr2[e] - a.w * Ti2[e];
        ci_[e][1] += a.z * Ti2[e] + a.w * Tr2[e];
        float nr = Tr2[e] * wr2[e] - Ti2[e] * wi2[e];
        float ni = Tr2[e] * wi2[e] + Ti2[e] * wr2[e];
        Tr2[e] = nr; Ti2[e] = ni;
      }
    }
    const float sc = 1.f / 16384.f;   // norm="forward"
    #pragma unroll
    for (int e = 0; e < 2; ++e) {
      int kxi = kxp + 16 * e;
      size_t o = (size_t)plane * 1024 + (size_t)kxi * 32 + kyp * 4;
      *(float4*)&Xf[o] = make_float4(cr_[e][0] * sc, ci_[e][0] * sc,
                                     cr_[e][1] * sc, ci_[e][1] * sc);
    }
  }
}

// ---------------------------------------------------------------------------
// Kernel 2: per-mode complex channel mix.
// block = (corner, x, c-group of 16); Y[b][c][kxi][ky][ri]
// ---------------------------------------------------------------------------
__global__ __launch_bounds__(256) void k_mix(const float* __restrict__ Xf,
                                             const float* __restrict__ w0r,
                                             const float* __restrict__ w0i,
                                             const float* __restrict__ w1r,
                                             const float* __restrict__ w1i,
                                             float* __restrict__ Y) {
  __shared__ float Ws[2][8][16][17];   // [ri][t][c][y]
  __shared__ float Xs[2][8][16][17];   // [ri][t][b][y]
  const int bid = blockIdx.x;          // 0..127
  const int cr = bid >> 6;
  const int x  = (bid >> 2) & 15;
  const int cg = bid & 3;
  const int c0 = cg * 16;
  const int kxi = cr * 16 + x;
  const float* Wr_g = cr ? w1r : w0r;
  const float* Wi_g = cr ? w1i : w0i;
  const int tid = threadIdx.x;
  const int y = tid & 15;
  const int s = tid >> 4;
  const int b0  = (s >> 2) * 4;
  const int cc0 = (s & 3) * 4;
  float accR[4][4] = {}, accI[4][4] = {};

  for (int tc = 0; tc < 8; ++tc) {
    const int tb = tc * 8;
    __syncthreads();
    #pragma unroll
    for (int k = 0; k < 8; ++k) {
      int i = tid + k * 256;           // 0..2047
      int y_ = i & 15, t_ = (i >> 4) & 7, c_ = i >> 7;
      size_t ga = ((size_t)(c0 + c_) * 64 + (tb + t_)) * 256 + x * 16 + y_;
      Ws[0][t_][c_][y_] = Wr_g[ga];
      Ws[1][t_][c_][y_] = Wi_g[ga];
    }
    #pragma unroll
    for (int k = 0; k < 8; ++k) {
      int i = tid + k * 256;
      int y_ = i & 15, t_ = (i >> 4) & 7, b_ = i >> 7;
      const float2 v =
          *(const float2*)&Xf[(((size_t)b_ * 64 + (tb + t_)) * 32 + kxi) * 32 + y_ * 2];
      Xs[0][t_][b_][y_] = v.x;
      Xs[1][t_][b_][y_] = v.y;
    }
    __syncthreads();
    #pragma unroll
    for (int t = 0; t < 8; ++t) {
      float xr[4], xi[4], wr[4], wi[4];
      #pragma unroll
      for (int j = 0; j < 4; ++j) {
        xr[j] = Xs[0][t][b0 + j][y];
        xi[j] = Xs[1][t][b0 + j][y];
        wr[j] = Ws[0][t][cc0 + j][y];
        wi[j] = Ws[1][t][cc0 + j][y];
      }
      #pragma unroll
      for (int bj = 0; bj < 4; ++bj)
        #pragma unroll
        for (int cj = 0; cj < 4; ++cj) {
          accR[bj][cj] = fmaf(xr[bj], wr[cj], accR[bj][cj]);
          accR[bj][cj] = fmaf(-xi[bj], wi[cj], accR[bj][cj]);
          accI[bj][cj] = fmaf(xr[bj], wi[cj], accI[bj][cj]);
          accI[bj][cj] = fmaf(xi[bj], wr[cj], accI[bj][cj]);
        }
    }
  }
  #pragma unroll
  for (int bj = 0; bj < 4; ++bj)
    #pragma unroll
    for (int cj = 0; cj < 4; ++cj) {
      size_t ya = (((size_t)(b0 + bj) * 64 + (c0 + cc0 + cj)) * 32 + kxi) * 32 +
                  (size_t)y * 2;
      *(float2*)&Y[ya] = make_float2(accR[bj][cj], accI[bj][cj]);
    }
}

// ---------------------------------------------------------------------------
// Kernel 3: per (b,c) plane: Y modes -> out[128][128]
// phase A: Z[h][ky] = sum_kx Y[kx][ky] e^{+2pi i kx h/128}   -> Mc/Ms in LDS
// phase B: out[h][w] = sum_k Mc[k][h] cos(2pi k w/128) + Ms[k][h] sin(...)
//          (Mc = f*Zr, Ms = -f*Zi, f = 1 for k=0 else 2; Im of DC discarded
//           exactly as numpy irfft does)
// ---------------------------------------------------------------------------
__global__ __launch_bounds__(256) void k_inv(const float* __restrict__ Y,
                                             float* __restrict__ out) {
  __shared__ float Yl[1024];
  __shared__ float Mc[16][132];
  __shared__ float Ms[16][132];
  const int plane = blockIdx.x;   // b*64 + c
  const int tid = threadIdx.x;
  {
    float4 v = *(const float4*)&Y[(size_t)plane * 1024 + tid * 4];
    *(float4*)&Yl[tid * 4] = v;
  }
  __syncthreads();

  if (tid < 128) {
    const int hq = tid >> 2;     // h set 4hq..4hq+3
    const int kg = tid & 3;      // ky set 4kg..4kg+3
    float zr[4][4] = {}, zi[4][4] = {};
    float wr[4], wi[4], Tr[4], Ti[4];
    #pragma unroll
    for (int hj = 0; hj < 4; ++hj) {
      float h = (float)(4 * hq + hj);
      __sincosf(PI2 * h / 128.f, &wi[hj], &wr[hj]);
      Tr[hj] = 1.f; Ti[hj] = 0.f;
    }
    #pragma unroll 4
    for (int kxi = 0; kxi < 16; ++kxi) {
      float4 ya = *(float4*)&Yl[kxi * 32 + kg * 8];
      float4 yb = *(float4*)&Yl[kxi * 32 + kg * 8 + 4];
      #pragma unroll
      for (int hj = 0; hj < 4; ++hj) {
        zr[hj][0] += ya.x * Tr[hj] - ya.y * Ti[hj];
        zi[hj][0] += ya.x * Ti[hj] + ya.y * Tr[hj];
        zr[hj][1] += ya.z * Tr[hj] - ya.w * Ti[hj];
        zi[hj][1] += ya.z * Ti[hj] + ya.w * Tr[hj];
        zr[hj][2] += yb.x * Tr[hj] - yb.y * Ti[hj];
        zi[hj][2] += yb.x * Ti[hj] + yb.y * Tr[hj];
        zr[hj][3] += yb.z * Tr[hj] - yb.w * Ti[hj];
        zi[hj][3] += yb.z * Ti[hj] + yb.w * Tr[hj];
        float nr = Tr[hj] * wr[hj] - Ti[hj] * wi[hj];
        float ni = Tr[hj] * wi[hj] + Ti[hj] * wr[hj];
        Tr[hj] = nr; Ti[hj] = ni;
      }
    }
    // bottom corner starts at kx = 112 == -16: T = e^{-i pi h/4}
    #pragma unroll
    for (int hj = 0; hj < 4; ++hj) {
      float h = (float)(4 * hq + hj);
      __sincosf(-3.14159265358979323846f * h / 4.f, &Ti[hj], &Tr[hj]);
    }
    #pragma unroll 4
    for (int kxi = 16; kxi < 32; ++kxi) {
      float4 ya = *(float4*)&Yl[kxi * 32 + kg * 8];
      float4 yb = *(float4*)&Yl[kxi * 32 + kg * 8 + 4];
      #pragma unroll
      for (int hj = 0; hj < 4; ++hj) {
        zr[hj][0] += ya.x * Tr[hj] - ya.y * Ti[hj];
        zi[hj][0] += ya.x * Ti[hj] + ya.y * Tr[hj];
        zr[hj][1] += ya.z * Tr[hj] - ya.w * Ti[hj];
        zi[hj][1] += ya.z * Ti[hj] + ya.w * Tr[hj];
        zr[hj][2] += yb.x * Tr[hj] - yb.y * Ti[hj];
        zi[hj][2] += yb.x * Ti[hj] + yb.y * Tr[hj];
        zr[hj][3] += yb.z * Tr[hj] - yb.w * Ti[hj];
        zi[hj][3] += yb.z * Ti[hj] + yb.w * Tr[hj];
        float nr = Tr[hj] * wr[hj] - Ti[hj] * wi[hj];
        float ni = Tr[hj] * wi[hj] + Ti[hj] * wr[hj];
        Tr[hj] = nr; Ti[hj] = ni;
      }
    }
    #pragma unroll
    for (int kyj = 0; kyj < 4; ++kyj) {
      int k = 4 * kg + kyj;
      float f = (k == 0) ? 1.f : 2.f;
      #pragma unroll
      for (int hj = 0; hj < 4; ++hj) {
        Mc[k][4 * hq + hj] =  f * zr[hj][kyj];
        Ms[k][4 * hq + hj] = -f * zi[hj][kyj];
      }
    }
  }
  __syncthreads();

  // phase B: thread = (ht, wt): rows 8ht..8ht+7, cols {4wt..+3} and +64
  const int ht = tid >> 4;
  const int wt = tid & 15;
  float acc0[8][4] = {}, acc1[8][4] = {};
  float Ur[4], Ui[4], owr[4], owi[4];
  #pragma unroll
  for (int wj = 0; wj < 4; ++wj) {
    float w = (float)(4 * wt + wj);
    __sincosf(PI2 * w / 128.f, &owi[wj], &owr[wj]);
    Ur[wj] = 1.f; Ui[wj] = 0.f;
  }
  #pragma unroll 4
  for (int k = 0; k < 16; ++k) {
    float mc[8], ms[8];
    *(float4*)&mc[0] = *(float4*)&Mc[k][8 * ht];
    *(float4*)&mc[4] = *(float4*)&Mc[k][8 * ht + 4];
    *(float4*)&ms[0] = *(float4*)&Ms[k][8 * ht];
    *(float4*)&ms[4] = *(float4*)&Ms[k][8 * ht + 4];
    const float sk = (k & 1) ? -1.f : 1.f;   // w+64: U -> (-1)^k U
    #pragma unroll
    for (int hj = 0; hj < 8; ++hj)
      #pragma unroll
      for (int wj = 0; wj < 4; ++wj) {
        float t = mc[hj] * Ur[wj] + ms[hj] * Ui[wj];
        acc0[hj][wj] += t;
        acc1[hj][wj] = fmaf(sk, t, acc1[hj][wj]);
      }
    #pragma unroll
    for (int wj = 0; wj < 4; ++wj) {
      float nr = Ur[wj] * owr[wj] - Ui[wj] * owi[wj];
      float ni = Ur[wj] * owi[wj] + Ui[wj] * owr[wj];
      Ur[wj] = nr; Ui[wj] = ni;
    }
  }
  float* op = out + (size_t)plane * (128 * 128);
  #pragma unroll
  for (int hj = 0; hj < 8; ++hj) {
    int h = 8 * ht + hj;
    *(float4*)&op[h * 128 + 4 * wt] =
        make_float4(acc0[hj][0], acc0[hj][1], acc0[hj][2], acc0[hj][3]);
    *(float4*)&op[h * 128 + 4 * wt + 64] =
        make_float4(acc1[hj][0], acc1[hj][1], acc1[hj][2], acc1[hj][3]);
  }
}

extern "C" void kernel_launch(void* const* d_in, const int* in_sizes, int n_in,
                              void* d_out, int out_size, void* d_ws, size_t ws_size,
                              hipStream_t stream) {
  const float* X   = (const float*)d_in[0];
  const float* w0r = (const float*)d_in[1];
  const float* w0i = (const float*)d_in[2];
  const float* w1r = (const float*)d_in[3];
  const float* w1i = (const float*)d_in[4];
  float* outp = (float*)d_out;
  float* Xf = (float*)d_ws;                  // 1M floats = 4 MB
  float* Yw = (float*)d_ws + (1u << 20);     // 1M floats = 4 MB
  k_fwd<<<1024, 256, 0, stream>>>(X, Xf);
  k_mix<<<128, 256, 0, stream>>>(Xf, w0r, w0i, w1r, w1i, Yw);
  k_inv<<<1024, 256, 0, stream>>>(Yw, outp);
}

// Round 2
// 183.107 us; speedup vs baseline: 1.1361x; 1.1361x over previous
//
#include <hip/hip_runtime.h>

#define PI2 6.28318530717958647692f

// ===========================================================================
// Kernel 1: per (b,t) plane.
// Phase 1: A2[kx][w] = sum_h X[h][w] e^{-2pi i kx h/128}, radix-2 fold over h.
// Phase 2: Xf[kx][ky] = sum_w A2[kx][w] e^{-2pi i ky w/128}, fold over w.
// kxi 0..15 -> kx=kxi ; kxi 16..31 -> kx=kxi+96. Scale 1/16384.
// Xf layout: [plane][kxi][ky][ri] (1024 dwords/plane).
// ===========================================================================
__global__ __launch_bounds__(256) void k_fwd(const float* __restrict__ X,
                                             float* __restrict__ Xf) {
  __shared__ __attribute__((aligned(16))) float E1t[64 * 32 * 2];   // [h<64][kxi] f2
  __shared__ __attribute__((aligned(16))) float A2t[128 * 34 * 2];  // [w][kxi(+2 pad)] f2
  __shared__ __attribute__((aligned(16))) float E2t[64 * 16 * 2];   // [w<64][ky] f2
  const int plane = blockIdx.x;
  const int tid = threadIdx.x;
  const float* Xp = X + (size_t)plane * (128 * 128);

  // ---- build twiddle tables (args reduced mod 128 for accuracy) ----
  #pragma unroll
  for (int k = 0; k < 8; ++k) {
    int idx = tid + k * 256;          // 2048 entries
    int h = idx >> 5, kxi = idx & 31;
    int kx = kxi + ((kxi >> 4) ? 96 : 0);
    float ang = -PI2 * (float)((kx * h) & 127) / 128.f;
    float s_, c_;
    __sincosf(ang, &s_, &c_);
    E1t[idx * 2] = c_; E1t[idx * 2 + 1] = s_;
  }
  #pragma unroll
  for (int k = 0; k < 4; ++k) {
    int idx = tid + k * 256;          // 1024 entries
    int w = idx >> 4, ky = idx & 15;
    float ang = -PI2 * (float)((ky * w) & 127) / 128.f;
    float s_, c_;
    __sincosf(ang, &s_, &c_);
    E2t[idx * 2] = c_; E2t[idx * 2 + 1] = s_;
  }
  __syncthreads();

  // ---- phase 1: thread = (w 0..127, kxg 0..1), 16 kxi each ----
  {
    const int w = tid & 127;
    const int kxg = tid >> 7;
    float cr[16], ci[16];
    #pragma unroll
    for (int j = 0; j < 16; ++j) { cr[j] = 0.f; ci[j] = 0.f; }
    float x0 = Xp[w], x1 = Xp[64 * 128 + w];
    for (int h = 0; h < 64; ++h) {
      float nx0 = 0.f, nx1 = 0.f;
      if (h < 63) { nx0 = Xp[(h + 1) * 128 + w]; nx1 = Xp[(h + 65) * 128 + w]; }
      float ue = x0 + x1;             // even kx
      float uo = x0 - x1;             // odd kx
      const float4* Erow = (const float4*)&E1t[(h * 32 + kxg * 16) * 2];
      #pragma unroll
      for (int j2 = 0; j2 < 8; ++j2) {
        float4 e = Erow[j2];          // (c_{2j2}, s_{2j2}, c_{2j2+1}, s_{2j2+1})
        cr[2 * j2]     = fmaf(ue, e.x, cr[2 * j2]);
        ci[2 * j2]     = fmaf(ue, e.y, ci[2 * j2]);
        cr[2 * j2 + 1] = fmaf(uo, e.z, cr[2 * j2 + 1]);
        ci[2 * j2 + 1] = fmaf(uo, e.w, ci[2 * j2 + 1]);
      }
      x0 = nx0; x1 = nx1;
    }
    #pragma unroll
    for (int j = 0; j < 16; ++j) {
      int f2i = w * 34 + kxg * 16 + j;
      A2t[f2i * 2] = cr[j]; A2t[f2i * 2 + 1] = ci[j];
    }
  }
  __syncthreads();

  // ---- phase 2: thread = (kxi 0..31, t 0..7); ky = {t, t+8} ----
  {
    const int kxi = tid >> 3;
    const int t = tid & 7;
    const float s = (t & 1) ? -1.f : 1.f;   // (-1)^ky, same for t and t+8
    float r0 = 0.f, i0 = 0.f, r1 = 0.f, i1 = 0.f;
    for (int w = 0; w < 64; ++w) {
      const float2 a = *(const float2*)&A2t[(w * 34 + kxi) * 2];
      const float2 b = *(const float2*)&A2t[((w + 64) * 34 + kxi) * 2];
      float ur = fmaf(s, b.x, a.x);
      float ui = fmaf(s, b.y, a.y);
      const float2 e0 = *(const float2*)&E2t[(w * 16 + t) * 2];
      const float2 e1 = *(const float2*)&E2t[(w * 16 + t + 8) * 2];
      r0 = fmaf(ur, e0.x, r0); r0 = fmaf(-ui, e0.y, r0);
      i0 = fmaf(ur, e0.y, i0); i0 = fmaf(ui, e0.x, i0);
      r1 = fmaf(ur, e1.x, r1); r1 = fmaf(-ui, e1.y, r1);
      i1 = fmaf(ur, e1.y, i1); i1 = fmaf(ui, e1.x, i1);
    }
    const float sc = 1.f / 16384.f;
    float* base = Xf + (size_t)plane * 1024 + kxi * 32;
    *(float2*)&base[t * 2]       = make_float2(r0 * sc, i0 * sc);
    *(float2*)&base[(t + 8) * 2] = make_float2(r1 * sc, i1 * sc);
  }
}

// ===========================================================================
// Kernel 2: channel mix. block = (corner 2, x 16, cg 16), c-tile of 4.
// thread = (b 16, y 16). Y[b][c][kxi][ky][ri], same layout as Xf.
// ===========================================================================
__global__ __launch_bounds__(256) void k_mix(const float* __restrict__ Xf,
                                             const float* __restrict__ w0r,
                                             const float* __restrict__ w0i,
                                             const float* __restrict__ w1r,
                                             const float* __restrict__ w1i,
                                             float* __restrict__ Y) {
  __shared__ __attribute__((aligned(16))) float Wl[4 * 64 * 16 * 2]; // [c][t][y] f2
  const int bid = blockIdx.x;               // 0..511
  const int c2 = bid >> 8;
  const int x  = (bid >> 4) & 15;
  const int cg = bid & 15;
  const int c0 = cg * 4;
  const int kxi = c2 * 16 + x;
  const float* Wr_g = c2 ? w1r : w0r;
  const float* Wi_g = c2 ? w1i : w0i;
  const int tid = threadIdx.x;
  const int b = tid >> 4;
  const int y = tid & 15;

  // stage weights: 4096 complex elements, coalesced (y fastest, 64B runs)
  #pragma unroll
  for (int k = 0; k < 16; ++k) {
    int idx = tid + k * 256;                // 0..4095
    int y_ = idx & 15, t_ = (idx >> 4) & 63, c_ = idx >> 10;
    size_t ga = (((size_t)(c0 + c_) * 64 + t_) * 16 + x) * 16 + y_;
    float wr = Wr_g[ga], wi = Wi_g[ga];
    Wl[idx * 2] = wr; Wl[idx * 2 + 1] = wi;
  }
  __syncthreads();

  float aR[4] = {}, aI[4] = {};
  const float* xbase = Xf + ((size_t)b * 64) * 1024 + kxi * 32 + y * 2;
  for (int t4 = 0; t4 < 64; t4 += 4) {
    float2 xv[4];
    #pragma unroll
    for (int q = 0; q < 4; ++q)
      xv[q] = *(const float2*)&xbase[(size_t)(t4 + q) * 1024];
    #pragma unroll
    for (int q = 0; q < 4; ++q) {
      int t = t4 + q;
      #pragma unroll
      for (int cj = 0; cj < 4; ++cj) {
        const float2 wv = *(const float2*)&Wl[((cj * 64 + t) * 16 + y) * 2];
        aR[cj] = fmaf(xv[q].x, wv.x, aR[cj]);
        aR[cj] = fmaf(-xv[q].y, wv.y, aR[cj]);
        aI[cj] = fmaf(xv[q].x, wv.y, aI[cj]);
        aI[cj] = fmaf(xv[q].y, wv.x, aI[cj]);
      }
    }
  }
  #pragma unroll
  for (int cj = 0; cj < 4; ++cj) {
    size_t ya = ((size_t)(b * 64 + c0 + cj)) * 1024 + kxi * 32 + y * 2;
    *(float2*)&Y[ya] = make_float2(aR[cj], aI[cj]);
  }
}

// ===========================================================================
// Kernel 3: per (b,c) plane inverse.
// Phase A: Z[h][ky] = sum_kxi Y[kxi][ky] e^{+2pi i kx h/128}; store
//          (Mc,Ms)[h][ky] = (f*Zr, -f*Zi), f = (ky==0)?1:2.
// Phase B: out[h][w] = sum_ky Mc*cos(2pi ky w/128) + Ms*sin(...),
//          folded over w / w+64 via ky parity.
// ===========================================================================
__global__ __launch_bounds__(256) void k_inv(const float* __restrict__ Y,
                                             float* __restrict__ out) {
  __shared__ __attribute__((aligned(16))) float Yl[1024];
  __shared__ __attribute__((aligned(16))) float Ml[128 * 18 * 2];  // [h][ky(+2 pad)] f2
  const int plane = blockIdx.x;
  const int tid = threadIdx.x;
  {
    *(float4*)&Yl[tid * 4] = *(const float4*)&Y[(size_t)plane * 1024 + tid * 4];
  }
  __syncthreads();

  // ---- phase A: thread = (g 0..1 ky-half, h 0..127) ----
  {
    const int g = tid >> 7;
    const int h = tid & 127;
    float zr[8] = {}, zi[8] = {};
    float uw, uwi;   // U = e^{+2pi i h/128}
    __sincosf(PI2 * (float)h / 128.f, &uwi, &uw);
    const float4* Yl4 = (const float4*)Yl;
    // run 1: kxi 0..15 (kx=0..15), T starts at 1
    float Tr = 1.f, Ti = 0.f;
    #pragma unroll 4
    for (int kxi = 0; kxi < 16; ++kxi) {
      #pragma unroll
      for (int q = 0; q < 4; ++q) {
        float4 p = Yl4[kxi * 8 + g * 4 + q];
        int m = 2 * q;
        zr[m]   = fmaf(p.x, Tr, zr[m]);   zr[m]   = fmaf(-p.y, Ti, zr[m]);
        zi[m]   = fmaf(p.x, Ti, zi[m]);   zi[m]   = fmaf(p.y, Tr, zi[m]);
        zr[m+1] = fmaf(p.z, Tr, zr[m+1]); zr[m+1] = fmaf(-p.w, Ti, zr[m+1]);
        zi[m+1] = fmaf(p.z, Ti, zi[m+1]); zi[m+1] = fmaf(p.w, Tr, zi[m+1]);
      }
      float nr = Tr * uw - Ti * uwi, ni = Tr * uwi + Ti * uw;
      Tr = nr; Ti = ni;
    }
    // run 2: kxi 16..31 (kx=112..127), T starts at e^{+2pi i 112 h/128}
    __sincosf(PI2 * (float)((112 * h) & 127) / 128.f, &Ti, &Tr);
    #pragma unroll 4
    for (int kxi = 16; kxi < 32; ++kxi) {
      #pragma unroll
      for (int q = 0; q < 4; ++q) {
        float4 p = Yl4[kxi * 8 + g * 4 + q];
        int m = 2 * q;
        zr[m]   = fmaf(p.x, Tr, zr[m]);   zr[m]   = fmaf(-p.y, Ti, zr[m]);
        zi[m]   = fmaf(p.x, Ti, zi[m]);   zi[m]   = fmaf(p.y, Tr, zi[m]);
        zr[m+1] = fmaf(p.z, Tr, zr[m+1]); zr[m+1] = fmaf(-p.w, Ti, zr[m+1]);
        zi[m+1] = fmaf(p.z, Ti, zi[m+1]); zi[m+1] = fmaf(p.w, Tr, zi[m+1]);
      }
      float nr = Tr * uw - Ti * uwi, ni = Tr * uwi + Ti * uw;
      Tr = nr; Ti = ni;
    }
    #pragma unroll
    for (int m = 0; m < 8; ++m) {
      int ky = g * 8 + m;
      float f = (ky == 0) ? 1.f : 2.f;
      int f2i = h * 18 + ky;
      Ml[f2i * 2]     =  f * zr[m];
      Ml[f2i * 2 + 1] = -f * zi[m];
    }
  }
  __syncthreads();

  // ---- phase B: thread = (hq 0..3, w 0..63); 32 h each, outputs w and w+64 ----
  {
    const int hq = tid >> 6;
    const int w = tid & 63;
    float C[16], S[16];
    {
      float cw, sw;
      __sincosf(PI2 * (float)w / 128.f, &sw, &cw);
      C[0] = 1.f; S[0] = 0.f;
      #pragma unroll
      for (int k = 1; k < 16; ++k) {
        C[k] = C[k - 1] * cw - S[k - 1] * sw;
        S[k] = C[k - 1] * sw + S[k - 1] * cw;
      }
    }
    float* op = out + (size_t)plane * (128 * 128);
    const float4* Ml4 = (const float4*)Ml;
    for (int hj = 0; hj < 32; ++hj) {
      int h = hq * 32 + hj;
      float e = 0.f, o = 0.f;
      #pragma unroll
      for (int j2 = 0; j2 < 8; ++j2) {
        float4 m01 = Ml4[h * 9 + j2];   // (Mc,Ms) for ky=2j2, 2j2+1
        int k = 2 * j2;
        float t0 = m01.x * C[k] + m01.y * S[k];
        float t1 = m01.z * C[k + 1] + m01.w * S[k + 1];
        e += t0; o += t1;
      }
      op[h * 128 + w]      = e + o;
      op[h * 128 + w + 64] = e - o;
    }
  }
}

extern "C" void kernel_launch(void* const* d_in, const int* in_sizes, int n_in,
                              void* d_out, int out_size, void* d_ws, size_t ws_size,
                              hipStream_t stream) {
  const float* X   = (const float*)d_in[0];
  const float* w0r = (const float*)d_in[1];
  const float* w0i = (const float*)d_in[2];
  const float* w1r = (const float*)d_in[3];
  const float* w1i = (const float*)d_in[4];
  float* outp = (float*)d_out;
  float* Xf = (float*)d_ws;                  // 4 MB
  float* Yw = (float*)d_ws + (1u << 20);     // 4 MB
  k_fwd<<<1024, 256, 0, stream>>>(X, Xf);
  k_mix<<<512, 256, 0, stream>>>(Xf, w0r, w0i, w1r, w1i, Yw);
  k_inv<<<1024, 256, 0, stream>>>(Yw, outp);
}